// Round 4
// baseline (1314.672 us; speedup 1.0000x reference)
//
#include <hip/hip_runtime.h>
#include <cstdint>
#include <cstddef>

// Problem constants: B=4,S=2048 -> N=8192; I=K=4096; O=11008; G=128
#define N_ 8192
#define K_ 4096
#define O_ 11008
#define NT_ (K_ / 32)   // 128 K-slices of 32

typedef __bf16 bf16x8 __attribute__((ext_vector_type(8)));
typedef float f32x4 __attribute__((ext_vector_type(4)));

__device__ __forceinline__ uint16_t f2bf(float f) {
    // round-to-nearest-even fp32 -> bf16 (finite inputs)
    uint32_t u = __float_as_uint(f);
    u += 0x7fffu + ((u >> 16) & 1u);
    return (uint16_t)(u >> 16);
}
__device__ __forceinline__ float bf2f(uint16_t b) {
    return __uint_as_float(((uint32_t)b) << 16);
}
__device__ __forceinline__ float bfr(float f) { return bf2f(f2bf(f)); }

// compiler-only memory fence: keeps memory ops in their phase region without
// pinning the instruction scheduler (rule m141: sched_barrier(0) pins cost ~40%)
__device__ __forceinline__ void cfence() { asm volatile("" ::: "memory"); }

// async global(16B/lane) -> LDS (wave-uniform base + lane*16, linear dest)
__device__ __forceinline__ void async_cp16(const uint16_t* gsrc, uint16_t* ldst) {
    __builtin_amdgcn_global_load_lds(
        (__attribute__((address_space(1))) void*)gsrc,
        (__attribute__((address_space(3))) void*)ldst, 16, 0, 0);
}

// ---------------- pass 1: X fp32 -> bf16 ----------------
__global__ __launch_bounds__(256) void xcast(const float* __restrict__ X,
                                             uint16_t* __restrict__ Xb) {
    const size_t n4 = (size_t)N_ * K_ / 4;
    size_t i = (size_t)blockIdx.x * 256u + threadIdx.x;
    const size_t stride = (size_t)gridDim.x * 256u;
    for (; i < n4; i += stride) {
        float4 a = ((const float4*)X)[i];
        union { uint16_t u[4]; uint2 v; } r;
        r.u[0] = f2bf(a.x); r.u[1] = f2bf(a.y);
        r.u[2] = f2bf(a.z); r.u[3] = f2bf(a.w);
        ((uint2*)Xb)[i] = r.v;
    }
}

// ---------------- pass 2: dequant int32-codes -> bf16 W ----------------
// w = bf16( bf16((q-8)*s) + z ), matching the reference's bf16 elementwise chain.
__global__ __launch_bounds__(256) void wdeq(const int* __restrict__ Q,
                                            const float* __restrict__ SZ,
                                            uint16_t* __restrict__ Wb) {
    const size_t n4 = (size_t)O_ * K_ / 4;
    size_t i = (size_t)blockIdx.x * 256u + threadIdx.x;
    const size_t stride = (size_t)gridDim.x * 256u;
    for (; i < n4; i += stride) {
        const size_t e = i * 4;
        const size_t o = e >> 12;                    // / K_ (4096)
        const uint32_t g = ((uint32_t)e >> 7) & 31;  // 128-group
        const float2 sz = ((const float2*)SZ)[(size_t)g * O_ + o];
        const float s = bfr(sz.x);
        const float z = bfr(sz.y);
        int4 q = ((const int4*)Q)[i];
        union { uint16_t u[4]; uint2 v; } r;
        r.u[0] = f2bf(bfr((float)(q.x - 8) * s) + z);
        r.u[1] = f2bf(bfr((float)(q.y - 8) * s) + z);
        r.u[2] = f2bf(bfr((float)(q.z - 8) * s) + z);
        r.u[3] = f2bf(bfr((float)(q.w - 8) * s) + z);
        ((uint2*)Wb)[i] = r.v;
    }
}

// ---------------- pass 3: 256x256 tile, 8-phase-style pipelined MFMA GEMM ------
// 8 waves (2M x 4N), per-wave 128x64. LDS = 4-deep ring of K-slices (BK=32):
// sA[4][256*32] + sB[4][256*32] = 128 KiB. Per slice, two 16-MFMA sub-phases:
//   sub0: ds_read 4 B-frags + 4 A-frags(m0-3), issue STAGE_A(j+3), barrier,
//         setprio(1) 16 MFMA setprio(0), barrier
//   sub1: ds_read 4 A-frags(m4-7), issue STAGE_B(j+3), barrier,
//         setprio(1) 16 MFMA setprio(0)   [next slice's top barrier closes]
// Counted vmcnt at slice top: vmcnt(8) steady (slices j+1,j+2 in flight),
// tail 8->4->0. Never 0 in the main loop.
// Race-freedom: STAGE(j+3) targets the ring slot holding slice j-1, whose last
// ds_read was issued before the slice-j top barrier; the stage is issued after.
// No sched_barrier(0) anywhere (m141): only compiler memory fences — the
// scheduler stays free to place waitcnts / overlap addr-calc with MFMA.
// Swizzle (both-sides, rule #21): physical 16B slot = logical ^ ((row>>1)&3);
// LDS dest stays linear (global_load_lds), global source col pre-swizzled,
// ds_read addr swizzled. Within each 16-lane read group: 2-way (free).
__global__ __launch_bounds__(512, 2) void gemm_mfma8p(const uint16_t* __restrict__ A,
                                                      const uint16_t* __restrict__ B,
                                                      float* __restrict__ C) {
    __shared__ uint16_t sA[4][256 * 32];   // 4 x 16 KiB
    __shared__ uint16_t sB[4][256 * 32];   // 4 x 16 KiB  (128 KiB total)

    const int tid = threadIdx.x;
    const int l = tid & 63;
    const int w = tid >> 6;            // wave 0..7
    const int wm = w >> 2;             // 0..1  (M half: 128 rows)
    const int wn = w & 3;              // 0..3  (N quarter: 64 cols)
    const int n0 = blockIdx.x * 256;   // 32 tiles
    const int o0 = blockIdx.y * 256;   // 43 tiles

    // ---- staging addressing: thread t covers LDS rows (t>>2) and (t>>2)+128,
    // physical 16B slot (t&3); global k-slot = (t&3) ^ swz(row), swz=(row>>1)&3
    // = (t>>3)&3 (identical for both halves since 128 rows -> mod 4 = 0).
    const int gk = (((tid & 3) ^ ((tid >> 3) & 3)) & 3) * 8;   // elems
    const int sr0 = tid >> 2;                                   // row, q=0
    const uint16_t* gA0 = A + (size_t)(n0 + sr0) * K_ + gk;
    const uint16_t* gA1 = A + (size_t)(n0 + 128 + sr0) * K_ + gk;
    const uint16_t* gB0 = B + (size_t)(o0 + sr0) * K_ + gk;
    const uint16_t* gB1 = B + (size_t)(o0 + 128 + sr0) * K_ + gk;
    const int ldst = tid * 8;          // elem offset (t*16B); q=1 adds 4096 elems

    // ---- fragment read offsets: row-lane lr = l&15, logical slot l>>4,
    // physical slot = (l>>4) ^ ((row>>1)&3); row bits 1-2 == lr bits 1-2.
    const int lr = l & 15;
    const int cph = (((l >> 4) ^ ((l >> 1) & 3)) & 3) * 8;   // phys elem offset

    f32x4 acc[8][4] = {};

#define STAGE_A(j)                                                      \
    {                                                                   \
        const size_t ko = (size_t)(j) * 32;                             \
        uint16_t* d = &sA[(j) & 3][ldst];                               \
        async_cp16(gA0 + ko, d);                                        \
        async_cp16(gA1 + ko, d + 4096);                                 \
    }
#define STAGE_B(j)                                                      \
    {                                                                   \
        const size_t ko = (size_t)(j) * 32;                             \
        uint16_t* d = &sB[(j) & 3][ldst];                               \
        async_cp16(gB0 + ko, d);                                        \
        async_cp16(gB1 + ko, d + 4096);                                 \
    }

    // prologue: slices 0,1,2 (A+B each) = 12 loads in flight
    STAGE_A(0) STAGE_B(0)
    STAGE_A(1) STAGE_B(1)
    STAGE_A(2) STAGE_B(2)

    for (int j = 0; j < NT_; ++j) {
        // data-ready wait: everything up through B(j) landed; j+1,j+2 in flight
        if (j < NT_ - 2)       asm volatile("s_waitcnt vmcnt(8)" ::: "memory");
        else if (j == NT_ - 2) asm volatile("s_waitcnt vmcnt(4)" ::: "memory");
        else                   asm volatile("s_waitcnt vmcnt(0)" ::: "memory");
        __builtin_amdgcn_s_barrier();
        cfence();

        const uint16_t* tA = sA[j & 3];
        const uint16_t* tB = sB[j & 3];

        // ---- sub-phase 0: B all + A m0-3, stage A(j+3) ----
        bf16x8 bfrag[4], afrag[4];
#pragma unroll
        for (int n = 0; n < 4; ++n)
            bfrag[n] = *(const bf16x8*)&tB[(wn * 64 + n * 16 + lr) * 32 + cph];
#pragma unroll
        for (int m = 0; m < 4; ++m)
            afrag[m] = *(const bf16x8*)&tA[(wm * 128 + m * 16 + lr) * 32 + cph];
        if (j < NT_ - 3) STAGE_A(j + 3)
        cfence();
        __builtin_amdgcn_s_barrier();
        __builtin_amdgcn_s_setprio(1);
#pragma unroll
        for (int m = 0; m < 4; ++m)
#pragma unroll
            for (int n = 0; n < 4; ++n)
                acc[m][n] = __builtin_amdgcn_mfma_f32_16x16x32_bf16(afrag[m], bfrag[n], acc[m][n], 0, 0, 0);
        __builtin_amdgcn_s_setprio(0);
        __builtin_amdgcn_s_barrier();
        cfence();

        // ---- sub-phase 1: A m4-7 (B reused), stage B(j+3) ----
#pragma unroll
        for (int m = 0; m < 4; ++m)
            afrag[m] = *(const bf16x8*)&tA[(wm * 128 + 64 + m * 16 + lr) * 32 + cph];
        if (j < NT_ - 3) STAGE_B(j + 3)
        cfence();
        __builtin_amdgcn_s_barrier();
        __builtin_amdgcn_s_setprio(1);
#pragma unroll
        for (int m = 0; m < 4; ++m)
#pragma unroll
            for (int n = 0; n < 4; ++n)
                acc[m + 4][n] = __builtin_amdgcn_mfma_f32_16x16x32_bf16(afrag[m], bfrag[n], acc[m + 4][n], 0, 0, 0);
        __builtin_amdgcn_s_setprio(0);
        // next slice's top barrier closes this sub-phase
    }
#undef STAGE_A
#undef STAGE_B

    // C/D layout (verified rounds 1-3): col = lane&15, row = (lane>>4)*4 + reg
    const int rbase = (l >> 4) * 4;
#pragma unroll
    for (int m = 0; m < 8; ++m) {
#pragma unroll
        for (int n = 0; n < 4; ++n) {
#pragma unroll
            for (int r = 0; r < 4; ++r) {
                const size_t row = (size_t)(n0 + wm * 128 + m * 16 + rbase + r);
                C[row * O_ + (o0 + wn * 64 + n * 16 + lr)] = bfr(acc[m][n][r]);
            }
        }
    }
}

// ---------------- fallback: verified fp32 VALU kernel (previous session) -------
__global__ __launch_bounds__(256) void gemm_probe_f32sz(const float* __restrict__ X,
                                                        const int* __restrict__ Q,
                                                        const float* __restrict__ SZf,
                                                        float* __restrict__ C) {
    __shared__ float xs[32][64];
    __shared__ float ws[32][64];
    const int tid = threadIdx.x;
    const int n0 = blockIdx.x * 64;
    const int o0 = blockIdx.y * 64;
    const int tn = tid >> 4;
    const int to = tid & 15;
    const int srow = tid >> 2;
    const int skq = (tid & 3) * 8;

    float acc[4][4] = {};

    for (int k0 = 0; k0 < K_; k0 += 32) {
        {
            const float4* xp = (const float4*)(X + (size_t)(n0 + srow) * K_ + k0 + skq);
            float4 a = xp[0], b = xp[1];
            float v[8] = {a.x, a.y, a.z, a.w, b.x, b.y, b.z, b.w};
#pragma unroll
            for (int j = 0; j < 8; ++j) xs[skq + j][srow] = bfr(v[j]);
        }
        {
            const int o = o0 + srow;
            const uint32_t g = (uint32_t)k0 >> 7;
            const size_t p = (size_t)g * O_ + o;
            const float s = bfr(SZf[2 * p]);
            const float z = bfr(SZf[2 * p + 1]);
            const int4* qp = (const int4*)(Q + (size_t)o * K_ + k0 + skq);
            int4 qa = qp[0], qb = qp[1];
            int qs[8] = {qa.x, qa.y, qa.z, qa.w, qb.x, qb.y, qb.z, qb.w};
#pragma unroll
            for (int j = 0; j < 8; ++j) {
                float w1 = bfr((float)(qs[j] - 8) * s);
                ws[skq + j][srow] = bfr(w1 + z);
            }
        }
        __syncthreads();

#pragma unroll 8
        for (int kk = 0; kk < 32; ++kk) {
            const float4 xv = *(const float4*)&xs[kk][tn * 4];
            const float4 wv = *(const float4*)&ws[kk][to * 4];
            const float xa[4] = {xv.x, xv.y, xv.z, xv.w};
            const float wa[4] = {wv.x, wv.y, wv.z, wv.w};
#pragma unroll
            for (int i = 0; i < 4; ++i)
#pragma unroll
                for (int j = 0; j < 4; ++j)
                    acc[i][j] = fmaf(xa[i], wa[j], acc[i][j]);
        }
        __syncthreads();
    }

#pragma unroll
    for (int i = 0; i < 4; ++i) {
        const size_t row = (size_t)(n0 + tn * 4 + i);
#pragma unroll
        for (int j = 0; j < 4; ++j) {
            C[row * O_ + (o0 + to * 4 + j)] = bfr(acc[i][j]);
        }
    }
}

__global__ __launch_bounds__(256) void sentinel_fill(float* __restrict__ C, size_t n, float v) {
    size_t i = (size_t)blockIdx.x * 256u + threadIdx.x;
    size_t stride = (size_t)gridDim.x * 256u;
    for (; i < n; i += stride) C[i] = v;
}

extern "C" void kernel_launch(void* const* d_in, const int* in_sizes, int n_in,
                              void* d_out, int out_size, void* d_ws, size_t ws_size,
                              hipStream_t stream) {
    const float* x = (const float*)d_in[0];
    const int* q = (const int*)d_in[1];
    const float* szf = (const float*)d_in[2];
    float* out = (float*)d_out;

    float sentinel = 0.0f;
    if (n_in < 3)                         sentinel = 1000.0f;
    else if (in_sizes[0] != 33554432)     sentinel = 2000.0f;  // x: 8192*4096
    else if (in_sizes[1] != 45088768)     sentinel = 3000.0f;  // weight_q: 11008*4096
    else if (in_sizes[2] != 704512)       sentinel = 4000.0f;  // s&z: 32*11008*2
    else if (out_size   != 90177536)      sentinel = 5000.0f;  // 8192*11008

    if (sentinel != 0.0f) {
        sentinel_fill<<<8192, 256, 0, stream>>>(out, (size_t)out_size, sentinel);
        return;
    }

    const size_t xb_bytes = (size_t)N_ * K_ * 2;   // 67,108,864
    const size_t wb_bytes = (size_t)O_ * K_ * 2;   // 90,177,536

    if (ws_size >= xb_bytes + wb_bytes) {
        uint16_t* Xb = (uint16_t*)d_ws;
        uint16_t* Wb = (uint16_t*)((char*)d_ws + xb_bytes);
        xcast<<<2048, 256, 0, stream>>>(x, Xb);
        wdeq<<<2048, 256, 0, stream>>>(q, szf, Wb);
        dim3 grid(N_ / 256, O_ / 256);   // 32 x 43
        gemm_mfma8p<<<grid, 512, 0, stream>>>(Xb, Wb, out);
    } else {
        dim3 grid(N_ / 64, O_ / 64);
        gemm_probe_f32sz<<<grid, 256, 0, stream>>>(x, q, szf, out);
    }
}

// Round 5
// 1244.172 us; speedup vs baseline: 1.0567x; 1.0567x over previous
//
#include <hip/hip_runtime.h>
#include <cstdint>
#include <cstddef>

// Problem constants: B=4,S=2048 -> N=8192; I=K=4096; O=11008; G=128
#define N_ 8192
#define K_ 4096
#define O_ 11008
#define NT_ (K_ / 32)   // 128 K-slices of 32

typedef __bf16 bf16x8 __attribute__((ext_vector_type(8)));
typedef float f32x4 __attribute__((ext_vector_type(4)));

__device__ __forceinline__ uint16_t f2bf(float f) {
    // round-to-nearest-even fp32 -> bf16 (finite inputs)
    uint32_t u = __float_as_uint(f);
    u += 0x7fffu + ((u >> 16) & 1u);
    return (uint16_t)(u >> 16);
}
__device__ __forceinline__ float bf2f(uint16_t b) {
    return __uint_as_float(((uint32_t)b) << 16);
}
__device__ __forceinline__ float bfr(float f) { return bf2f(f2bf(f)); }

// async global(16B/lane) -> LDS (wave-uniform base + lane*16, linear dest)
__device__ __forceinline__ void async_cp16(const uint16_t* gsrc, uint16_t* ldst) {
    __builtin_amdgcn_global_load_lds(
        (__attribute__((address_space(1))) void*)gsrc,
        (__attribute__((address_space(3))) void*)ldst, 16, 0, 0);
}

// ---------------- pass 1: X fp32 -> bf16 (32B load / 16B store per iter) ------
__global__ __launch_bounds__(256) void xcast(const float* __restrict__ X,
                                             uint16_t* __restrict__ Xb) {
    const size_t n8 = (size_t)N_ * K_ / 8;
    size_t i = (size_t)blockIdx.x * 256u + threadIdx.x;
    const size_t stride = (size_t)gridDim.x * 256u;
    for (; i < n8; i += stride) {
        float4 a = ((const float4*)X)[2 * i];
        float4 b = ((const float4*)X)[2 * i + 1];
        union { uint16_t u[8]; uint4 v; } r;
        r.u[0] = f2bf(a.x); r.u[1] = f2bf(a.y); r.u[2] = f2bf(a.z); r.u[3] = f2bf(a.w);
        r.u[4] = f2bf(b.x); r.u[5] = f2bf(b.y); r.u[6] = f2bf(b.z); r.u[7] = f2bf(b.w);
        ((uint4*)Xb)[i] = r.v;
    }
}

// ---------------- pass 2: dequant int32-codes -> bf16 W (32B load / 16B store) -
// w = bf16( bf16((q-8)*s) + z ), matching the reference's bf16 elementwise chain.
__global__ __launch_bounds__(256) void wdeq(const int* __restrict__ Q,
                                            const float* __restrict__ SZ,
                                            uint16_t* __restrict__ Wb) {
    const size_t n8 = (size_t)O_ * K_ / 8;
    size_t i = (size_t)blockIdx.x * 256u + threadIdx.x;
    const size_t stride = (size_t)gridDim.x * 256u;
    for (; i < n8; i += stride) {
        const size_t e = i * 8;
        const size_t o = e >> 12;                    // / K_ (4096)
        const uint32_t g = ((uint32_t)e >> 7) & 31;  // 128-group (8 elems stay in one group)
        const float2 sz = ((const float2*)SZ)[(size_t)g * O_ + o];
        const float s = bfr(sz.x);
        const float z = bfr(sz.y);
        int4 qa = ((const int4*)Q)[2 * i];
        int4 qb = ((const int4*)Q)[2 * i + 1];
        int qs[8] = {qa.x, qa.y, qa.z, qa.w, qb.x, qb.y, qb.z, qb.w};
        union { uint16_t u[8]; uint4 v; } r;
#pragma unroll
        for (int j = 0; j < 8; ++j) {
            r.u[j] = f2bf(bfr((float)(qs[j] - 8) * s) + z);
        }
        ((uint4*)Wb)[i] = r.v;
    }
}

// ---------------- pass 3: 256x256 tile, single-region-per-slice MFMA GEMM ------
// 8 waves (2M x 4N), per-wave 128x64. LDS = 4-deep ring of K-slices (BK=32):
// sA[4][256*32] + sB[4][256*32] = 128 KiB. ONE barrier + one counted vmcnt per
// slice; the whole slice body {12 ds_read, 4 global_load_lds, 32 MFMA} is a
// single scheduler region — the compiler's fine-grained lgkmcnt overlaps LDS
// returns and staging with MFMA issue (r4 showed the barrier-locked alternation
// of read/MFMA regions was the stall, not scheduling pins).
// Race-freedom (1 barrier/slice):
//  - reads of slot j&3 in region j: vmcnt(8)+barrier at top of j => slice j's
//    staging landed for ALL waves before any wave reads.
//  - STAGE(j+3) writes slot (j+3)&3 == (j-1)&3: each wave's reads of that slot
//    (region j-1) are consumed by its own region-(j-1) MFMAs (compiler lgkmcnt)
//    => completed before the top-of-j barrier => before the stage issues.
//  - write-write on a slot: 4 slices apart, ordered by the counted vmcnt chain.
// Counted vmcnt: steady vmcnt(8) (slices j+1,j+2 in flight), tail 8->4->0.
// Swizzle (both-sides, rule #21): physical 16B slot = logical ^ ((row>>1)&3);
// LDS dest linear (global_load_lds), global source col pre-swizzled, ds_read
// addr swizzled. Within each 16-lane read group: 2-way (free).
__global__ __launch_bounds__(512, 2) void gemm_mfma1b(const uint16_t* __restrict__ A,
                                                      const uint16_t* __restrict__ B,
                                                      float* __restrict__ C) {
    __shared__ uint16_t sA[4][256 * 32];   // 4 x 16 KiB
    __shared__ uint16_t sB[4][256 * 32];   // 4 x 16 KiB  (128 KiB total)

    const int tid = threadIdx.x;
    const int l = tid & 63;
    const int w = tid >> 6;            // wave 0..7
    const int wm = w >> 2;             // 0..1  (M half: 128 rows)
    const int wn = w & 3;              // 0..3  (N quarter: 64 cols)
    const int n0 = blockIdx.x * 256;   // 32 tiles
    const int o0 = blockIdx.y * 256;   // 43 tiles

    // ---- staging addressing: thread t covers LDS rows (t>>2) and (t>>2)+128,
    // physical 16B slot (t&3); global k-slot = (t&3) ^ swz(row), swz=(row>>1)&3
    // = (t>>3)&3 (identical for both halves since 128 rows -> mod 4 = 0).
    const int gk = (((tid & 3) ^ ((tid >> 3) & 3)) & 3) * 8;   // elems
    const int sr0 = tid >> 2;                                   // row, q=0
    const uint16_t* gA0 = A + (size_t)(n0 + sr0) * K_ + gk;
    const uint16_t* gA1 = A + (size_t)(n0 + 128 + sr0) * K_ + gk;
    const uint16_t* gB0 = B + (size_t)(o0 + sr0) * K_ + gk;
    const uint16_t* gB1 = B + (size_t)(o0 + 128 + sr0) * K_ + gk;
    const int ldst = tid * 8;          // elem offset (t*16B); q=1 adds 4096 elems

    // ---- fragment read offsets: row-lane lr = l&15, logical slot l>>4,
    // physical slot = (l>>4) ^ ((row>>1)&3); row bits 1-2 == lr bits 1-2.
    const int lr = l & 15;
    const int cph = (((l >> 4) ^ ((l >> 1) & 3)) & 3) * 8;   // phys elem offset

    f32x4 acc[8][4] = {};

#define STAGE_A(j)                                                      \
    {                                                                   \
        const size_t ko = (size_t)(j) * 32;                             \
        uint16_t* d = &sA[(j) & 3][ldst];                               \
        async_cp16(gA0 + ko, d);                                        \
        async_cp16(gA1 + ko, d + 4096);                                 \
    }
#define STAGE_B(j)                                                      \
    {                                                                   \
        const size_t ko = (size_t)(j) * 32;                             \
        uint16_t* d = &sB[(j) & 3][ldst];                               \
        async_cp16(gB0 + ko, d);                                        \
        async_cp16(gB1 + ko, d + 4096);                                 \
    }

    // prologue: slices 0,1,2 (A+B each) = 12 loads in flight
    STAGE_A(0) STAGE_B(0)
    STAGE_A(1) STAGE_B(1)
    STAGE_A(2) STAGE_B(2)

    for (int j = 0; j < NT_; ++j) {
        // slice j landed (per-wave), j+1/j+2 in flight; barrier makes it global
        if (j < NT_ - 2)       asm volatile("s_waitcnt vmcnt(8)" ::: "memory");
        else if (j == NT_ - 2) asm volatile("s_waitcnt vmcnt(4)" ::: "memory");
        else                   asm volatile("s_waitcnt vmcnt(0)" ::: "memory");
        __builtin_amdgcn_s_barrier();

        const uint16_t* tA = sA[j & 3];
        const uint16_t* tB = sB[j & 3];

        // single region: frag reads + stage issue + MFMA, scheduler-free
        bf16x8 bfrag[4], afrag[8];
#pragma unroll
        for (int n = 0; n < 4; ++n)
            bfrag[n] = *(const bf16x8*)&tB[(wn * 64 + n * 16 + lr) * 32 + cph];
#pragma unroll
        for (int m = 0; m < 8; ++m)
            afrag[m] = *(const bf16x8*)&tA[(wm * 128 + m * 16 + lr) * 32 + cph];
        if (j < NT_ - 3) {
            STAGE_A(j + 3)
            STAGE_B(j + 3)
        }
        __builtin_amdgcn_s_setprio(1);
#pragma unroll
        for (int m = 0; m < 8; ++m)
#pragma unroll
            for (int n = 0; n < 4; ++n)
                acc[m][n] = __builtin_amdgcn_mfma_f32_16x16x32_bf16(afrag[m], bfrag[n], acc[m][n], 0, 0, 0);
        __builtin_amdgcn_s_setprio(0);
        // next slice's top vmcnt+barrier closes the region
    }
#undef STAGE_A
#undef STAGE_B

    // C/D layout (verified rounds 1-4): col = lane&15, row = (lane>>4)*4 + reg
    const int rbase = (l >> 4) * 4;
#pragma unroll
    for (int m = 0; m < 8; ++m) {
#pragma unroll
        for (int n = 0; n < 4; ++n) {
#pragma unroll
            for (int r = 0; r < 4; ++r) {
                const size_t row = (size_t)(n0 + wm * 128 + m * 16 + rbase + r);
                C[row * O_ + (o0 + wn * 64 + n * 16 + lr)] = bfr(acc[m][n][r]);
            }
        }
    }
}

// ---------------- fallback: verified fp32 VALU kernel (previous session) -------
__global__ __launch_bounds__(256) void gemm_probe_f32sz(const float* __restrict__ X,
                                                        const int* __restrict__ Q,
                                                        const float* __restrict__ SZf,
                                                        float* __restrict__ C) {
    __shared__ float xs[32][64];
    __shared__ float ws[32][64];
    const int tid = threadIdx.x;
    const int n0 = blockIdx.x * 64;
    const int o0 = blockIdx.y * 64;
    const int tn = tid >> 4;
    const int to = tid & 15;
    const int srow = tid >> 2;
    const int skq = (tid & 3) * 8;

    float acc[4][4] = {};

    for (int k0 = 0; k0 < K_; k0 += 32) {
        {
            const float4* xp = (const float4*)(X + (size_t)(n0 + srow) * K_ + k0 + skq);
            float4 a = xp[0], b = xp[1];
            float v[8] = {a.x, a.y, a.z, a.w, b.x, b.y, b.z, b.w};
#pragma unroll
            for (int j = 0; j < 8; ++j) xs[skq + j][srow] = bfr(v[j]);
        }
        {
            const int o = o0 + srow;
            const uint32_t g = (uint32_t)k0 >> 7;
            const size_t p = (size_t)g * O_ + o;
            const float s = bfr(SZf[2 * p]);
            const float z = bfr(SZf[2 * p + 1]);
            const int4* qp = (const int4*)(Q + (size_t)o * K_ + k0 + skq);
            int4 qa = qp[0], qb = qp[1];
            int qs[8] = {qa.x, qa.y, qa.z, qa.w, qb.x, qb.y, qb.z, qb.w};
#pragma unroll
            for (int j = 0; j < 8; ++j) {
                float w1 = bfr((float)(qs[j] - 8) * s);
                ws[skq + j][srow] = bfr(w1 + z);
            }
        }
        __syncthreads();

#pragma unroll 8
        for (int kk = 0; kk < 32; ++kk) {
            const float4 xv = *(const float4*)&xs[kk][tn * 4];
            const float4 wv = *(const float4*)&ws[kk][to * 4];
            const float xa[4] = {xv.x, xv.y, xv.z, xv.w};
            const float wa[4] = {wv.x, wv.y, wv.z, wv.w};
#pragma unroll
            for (int i = 0; i < 4; ++i)
#pragma unroll
                for (int j = 0; j < 4; ++j)
                    acc[i][j] = fmaf(xa[i], wa[j], acc[i][j]);
        }
        __syncthreads();
    }

#pragma unroll
    for (int i = 0; i < 4; ++i) {
        const size_t row = (size_t)(n0 + tn * 4 + i);
#pragma unroll
        for (int j = 0; j < 4; ++j) {
            C[row * O_ + (o0 + to * 4 + j)] = bfr(acc[i][j]);
        }
    }
}

__global__ __launch_bounds__(256) void sentinel_fill(float* __restrict__ C, size_t n, float v) {
    size_t i = (size_t)blockIdx.x * 256u + threadIdx.x;
    size_t stride = (size_t)gridDim.x * 256u;
    for (; i < n; i += stride) C[i] = v;
}

extern "C" void kernel_launch(void* const* d_in, const int* in_sizes, int n_in,
                              void* d_out, int out_size, void* d_ws, size_t ws_size,
                              hipStream_t stream) {
    const float* x = (const float*)d_in[0];
    const int* q = (const int*)d_in[1];
    const float* szf = (const float*)d_in[2];
    float* out = (float*)d_out;

    float sentinel = 0.0f;
    if (n_in < 3)                         sentinel = 1000.0f;
    else if (in_sizes[0] != 33554432)     sentinel = 2000.0f;  // x: 8192*4096
    else if (in_sizes[1] != 45088768)     sentinel = 3000.0f;  // weight_q: 11008*4096
    else if (in_sizes[2] != 704512)       sentinel = 4000.0f;  // s&z: 32*11008*2
    else if (out_size   != 90177536)      sentinel = 5000.0f;  // 8192*11008

    if (sentinel != 0.0f) {
        sentinel_fill<<<8192, 256, 0, stream>>>(out, (size_t)out_size, sentinel);
        return;
    }

    const size_t xb_bytes = (size_t)N_ * K_ * 2;   // 67,108,864
    const size_t wb_bytes = (size_t)O_ * K_ * 2;   // 90,177,536

    if (ws_size >= xb_bytes + wb_bytes) {
        uint16_t* Xb = (uint16_t*)d_ws;
        uint16_t* Wb = (uint16_t*)((char*)d_ws + xb_bytes);
        xcast<<<4096, 256, 0, stream>>>(x, Xb);
        wdeq<<<4096, 256, 0, stream>>>(q, szf, Wb);
        dim3 grid(N_ / 256, O_ / 256);   // 32 x 43
        gemm_mfma1b<<<grid, 512, 0, stream>>>(Xb, Wb, out);
    } else {
        dim3 grid(N_ / 64, O_ / 64);
        gemm_probe_f32sz<<<grid, 256, 0, stream>>>(x, q, szf, out);
    }
}

// Round 7
// 1224.690 us; speedup vs baseline: 1.0735x; 1.0159x over previous
//
#include <hip/hip_runtime.h>
#include <cstdint>
#include <cstddef>

// Problem constants: B=4,S=2048 -> N=8192; I=K=4096; O=11008; G=128
#define N_ 8192
#define K_ 4096
#define O_ 11008
#define NT_ (K_ / 32)   // 128 K-slices of 32

typedef __bf16 bf16x8 __attribute__((ext_vector_type(8)));
typedef float f32x4 __attribute__((ext_vector_type(4)));

__device__ __forceinline__ uint16_t f2bf(float f) {
    // round-to-nearest-even fp32 -> bf16 (finite inputs)
    uint32_t u = __float_as_uint(f);
    u += 0x7fffu + ((u >> 16) & 1u);
    return (uint16_t)(u >> 16);
}
__device__ __forceinline__ float bf2f(uint16_t b) {
    return __uint_as_float(((uint32_t)b) << 16);
}
__device__ __forceinline__ float bfr(float f) { return bf2f(f2bf(f)); }

// async global(16B/lane) -> LDS (wave-uniform base + lane*16, linear dest)
__device__ __forceinline__ void async_cp16(const uint16_t* gsrc, uint16_t* ldst) {
    __builtin_amdgcn_global_load_lds(
        (__attribute__((address_space(1))) void*)gsrc,
        (__attribute__((address_space(3))) void*)ldst, 16, 0, 0);
}

// ---------------- pass 1: X fp32 -> bf16 (32B load / 16B store per iter) ------
__global__ __launch_bounds__(256) void xcast(const float* __restrict__ X,
                                             uint16_t* __restrict__ Xb) {
    const size_t n8 = (size_t)N_ * K_ / 8;
    size_t i = (size_t)blockIdx.x * 256u + threadIdx.x;
    const size_t stride = (size_t)gridDim.x * 256u;
    for (; i < n8; i += stride) {
        float4 a = ((const float4*)X)[2 * i];
        float4 b = ((const float4*)X)[2 * i + 1];
        union { uint16_t u[8]; uint4 v; } r;
        r.u[0] = f2bf(a.x); r.u[1] = f2bf(a.y); r.u[2] = f2bf(a.z); r.u[3] = f2bf(a.w);
        r.u[4] = f2bf(b.x); r.u[5] = f2bf(b.y); r.u[6] = f2bf(b.z); r.u[7] = f2bf(b.w);
        ((uint4*)Xb)[i] = r.v;
    }
}

// ---------------- pass 2: dequant int32-codes -> bf16 W (32B load / 16B store) -
// w = bf16( bf16((q-8)*s) + z ), matching the reference's bf16 elementwise chain.
__global__ __launch_bounds__(256) void wdeq(const int* __restrict__ Q,
                                            const float* __restrict__ SZ,
                                            uint16_t* __restrict__ Wb) {
    const size_t n8 = (size_t)O_ * K_ / 8;
    size_t i = (size_t)blockIdx.x * 256u + threadIdx.x;
    const size_t stride = (size_t)gridDim.x * 256u;
    for (; i < n8; i += stride) {
        const size_t e = i * 8;
        const size_t o = e >> 12;                    // / K_ (4096)
        const uint32_t g = ((uint32_t)e >> 7) & 31;  // 128-group (8 elems stay in one group)
        const float2 sz = ((const float2*)SZ)[(size_t)g * O_ + o];
        const float s = bfr(sz.x);
        const float z = bfr(sz.y);
        int4 qa = ((const int4*)Q)[2 * i];
        int4 qb = ((const int4*)Q)[2 * i + 1];
        int qs[8] = {qa.x, qa.y, qa.z, qa.w, qb.x, qb.y, qb.z, qb.w};
        union { uint16_t u[8]; uint4 v; } r;
#pragma unroll
        for (int j = 0; j < 8; ++j) {
            r.u[j] = f2bf(bfr((float)(qs[j] - 8) * s) + z);
        }
        ((uint4*)Wb)[i] = r.v;
    }
}

// ---------------- pass 3: 256x256 tile, cross-slice register-pipelined GEMM ----
// 8 waves (2M x 4N), per-wave 128x64. LDS = 4-deep ring of K-slices (BK=32):
// sA[4][256*32] + sB[4][256*32] = 128 KiB.
// r5 post-mortem: LDS-read cycles (~1152/CU-slice) and MFMA cycles (~1242)
// were ADDING (measured 2366) because each slice's reads fed the same slice's
// MFMAs. This version reads slice j+1's frags at the END of body j, so body
// j's MFMAs start on registers (no LDS wait) and the 12 ds_reads interleave
// with the 32 MFMAs (WAR-only deps, released frag-by-frag).
//   body j: { STAGE(j+3); 32 MFMA(frags_j); vmcnt(8); barrier; RD(frags_j+1) }
// Counted vmcnt: after STAGE(j+3), outstanding = {j+1, j+2, j+3} (12 loads);
// vmcnt(8) completes stage j+1 (oldest). Tail: body NT-3 -> vmcnt(4),
// body NT-2 -> vmcnt(0), body NT-1 -> no read. Never drains mid-loop.
// Race-freedom:
//  - RD of slot (j+1)&3: own stages landed (vmcnt), others' landed because
//    every wave passed its own vmcnt(8) before the barrier.
//  - STAGE(j+3) overwrites slot holding slice j-1: slice j-1's frags were
//    read at end of body j-2 and lgkmcnt-consumed by body j-1's MFMAs, which
//    precede body j-1's barrier (all waves); STAGE(j+3) issues after this
//    wave passed that barrier. Write-write: 4 slices apart via vmcnt chain.
// Swizzle (both-sides, rule #21): physical 16B slot = logical ^ ((row>>1)&3);
// LDS dest linear (global_load_lds), global source col pre-swizzled, ds_read
// addr swizzled. Within each 16-lane read group: 2-way (free).
__global__ __launch_bounds__(512, 2) void gemm_pipe(const uint16_t* __restrict__ A,
                                                    const uint16_t* __restrict__ B,
                                                    float* __restrict__ C) {
    __shared__ uint16_t sA[4][256 * 32];   // 4 x 16 KiB
    __shared__ uint16_t sB[4][256 * 32];   // 4 x 16 KiB  (128 KiB total)

    const int tid = threadIdx.x;
    const int l = tid & 63;
    const int w = tid >> 6;            // wave 0..7
    const int wm = w >> 2;             // 0..1  (M half: 128 rows)
    const int wn = w & 3;              // 0..3  (N quarter: 64 cols)
    const int n0 = blockIdx.x * 256;   // 32 tiles
    const int o0 = blockIdx.y * 256;   // 43 tiles

    // staging: thread t covers LDS rows (t>>2) and (t>>2)+128, physical 16B
    // slot (t&3); global k-slot = (t&3) ^ swz(row), swz = (row>>1)&3 = (t>>3)&3.
    const int gk = (((tid & 3) ^ ((tid >> 3) & 3)) & 3) * 8;   // elems
    const int sr0 = tid >> 2;
    const uint16_t* gA0 = A + (size_t)(n0 + sr0) * K_ + gk;
    const uint16_t* gA1 = A + (size_t)(n0 + 128 + sr0) * K_ + gk;
    const uint16_t* gB0 = B + (size_t)(o0 + sr0) * K_ + gk;
    const uint16_t* gB1 = B + (size_t)(o0 + 128 + sr0) * K_ + gk;
    const int ldst = tid * 8;          // elem offset (t*16B); q=1 adds 4096

    // fragment reads: row-lane lr = l&15, logical slot l>>4,
    // physical slot = (l>>4) ^ ((row>>1)&3); row bits 1-2 == lr bits 1-2.
    const int lr = l & 15;
    const int cph = (((l >> 4) ^ ((l >> 1) & 3)) & 3) * 8;

    f32x4 acc[8][4] = {};
    bf16x8 fa[8], fb[4];

#define STAGE_AB(j)                                                     \
    {                                                                   \
        const size_t ko = (size_t)(j) * 32;                             \
        const int sl = (j) & 3;                                         \
        uint16_t* dA = &sA[sl][ldst];                                   \
        uint16_t* dB = &sB[sl][ldst];                                   \
        async_cp16(gA0 + ko, dA);                                       \
        async_cp16(gA1 + ko, dA + 4096);                                \
        async_cp16(gB0 + ko, dB);                                       \
        async_cp16(gB1 + ko, dB + 4096);                                \
    }

#define RD_FRAGS(slot)                                                  \
    {                                                                   \
        const uint16_t* tB = sB[slot];                                  \
        const uint16_t* tA = sA[slot];                                  \
        _Pragma("unroll") for (int n = 0; n < 4; ++n)                   \
            fb[n] = *(const bf16x8*)&tB[(wn * 64 + n * 16 + lr) * 32 + cph]; \
        _Pragma("unroll") for (int m = 0; m < 8; ++m)                   \
            fa[m] = *(const bf16x8*)&tA[(wm * 128 + m * 16 + lr) * 32 + cph]; \
    }

#define MFMA_ALL                                                        \
    __builtin_amdgcn_s_setprio(1);                                      \
    _Pragma("unroll") for (int m = 0; m < 8; ++m)                       \
        _Pragma("unroll") for (int n = 0; n < 4; ++n)                   \
            acc[m][n] = __builtin_amdgcn_mfma_f32_16x16x32_bf16(        \
                fa[m], fb[n], acc[m][n], 0, 0, 0);                      \
    __builtin_amdgcn_s_setprio(0);

    // prologue: stage slices 0,1,2 (12 loads); wait slice 0; read frags_0
    STAGE_AB(0) STAGE_AB(1) STAGE_AB(2)
    asm volatile("s_waitcnt vmcnt(8)" ::: "memory");
    __builtin_amdgcn_s_barrier();
    RD_FRAGS(0)

    // steady bodies 0..NT_-4: stage j+3, MFMA j, wait(8), barrier, read j+1
    for (int j = 0; j < NT_ - 3; ++j) {
        STAGE_AB(j + 3)
        MFMA_ALL
        asm volatile("s_waitcnt vmcnt(8)" ::: "memory");
        __builtin_amdgcn_s_barrier();
        RD_FRAGS((j + 1) & 3)
    }
    // body NT_-3: no stage; wait(4) -> slice NT_-2 landed
    MFMA_ALL
    asm volatile("s_waitcnt vmcnt(4)" ::: "memory");
    __builtin_amdgcn_s_barrier();
    RD_FRAGS((NT_ - 2) & 3)
    // body NT_-2: wait(0) -> slice NT_-1 landed
    MFMA_ALL
    asm volatile("s_waitcnt vmcnt(0)" ::: "memory");
    __builtin_amdgcn_s_barrier();
    RD_FRAGS((NT_ - 1) & 3)
    // body NT_-1: final MFMAs, no read
    MFMA_ALL

#undef STAGE_AB
#undef RD_FRAGS
#undef MFMA_ALL

    // C/D layout (verified rounds 1-5): col = lane&15, row = (lane>>4)*4 + reg
    const int rbase = (l >> 4) * 4;
#pragma unroll
    for (int m = 0; m < 8; ++m) {
#pragma unroll
        for (int n = 0; n < 4; ++n) {
#pragma unroll
            for (int r = 0; r < 4; ++r) {
                const size_t row = (size_t)(n0 + wm * 128 + m * 16 + rbase + r);
                C[row * O_ + (o0 + wn * 64 + n * 16 + lr)] = bfr(acc[m][n][r]);
            }
        }
    }
}

// ---------------- fallback: verified fp32 VALU kernel (previous session) -------
__global__ __launch_bounds__(256) void gemm_probe_f32sz(const float* __restrict__ X,
                                                        const int* __restrict__ Q,
                                                        const float* __restrict__ SZf,
                                                        float* __restrict__ C) {
    __shared__ float xs[32][64];
    __shared__ float ws[32][64];
    const int tid = threadIdx.x;
    const int n0 = blockIdx.x * 64;
    const int o0 = blockIdx.y * 64;
    const int tn = tid >> 4;
    const int to = tid & 15;
    const int srow = tid >> 2;
    const int skq = (tid & 3) * 8;

    float acc[4][4] = {};

    for (int k0 = 0; k0 < K_; k0 += 32) {
        {
            const float4* xp = (const float4*)(X + (size_t)(n0 + srow) * K_ + k0 + skq);
            float4 a = xp[0], b = xp[1];
            float v[8] = {a.x, a.y, a.z, a.w, b.x, b.y, b.z, b.w};
#pragma unroll
            for (int j = 0; j < 8; ++j) xs[skq + j][srow] = bfr(v[j]);
        }
        {
            const int o = o0 + srow;
            const uint32_t g = (uint32_t)k0 >> 7;
            const size_t p = (size_t)g * O_ + o;
            const float s = bfr(SZf[2 * p]);
            const float z = bfr(SZf[2 * p + 1]);
            const int4* qp = (const int4*)(Q + (size_t)o * K_ + k0 + skq);
            int4 qa = qp[0], qb = qp[1];
            int qs[8] = {qa.x, qa.y, qa.z, qa.w, qb.x, qb.y, qb.z, qb.w};
#pragma unroll
            for (int j = 0; j < 8; ++j) {
                float w1 = bfr((float)(qs[j] - 8) * s);
                ws[skq + j][srow] = bfr(w1 + z);
            }
        }
        __syncthreads();

#pragma unroll 8
        for (int kk = 0; kk < 32; ++kk) {
            const float4 xv = *(const float4*)&xs[kk][tn * 4];
            const float4 wv = *(const float4*)&ws[kk][to * 4];
            const float xa[4] = {xv.x, xv.y, xv.z, xv.w};
            const float wa[4] = {wv.x, wv.y, wv.z, wv.w};
#pragma unroll
            for (int i = 0; i < 4; ++i)
#pragma unroll
                for (int j = 0; j < 4; ++j)
                    acc[i][j] = fmaf(xa[i], wa[j], acc[i][j]);
        }
        __syncthreads();
    }

#pragma unroll
    for (int i = 0; i < 4; ++i) {
        const size_t row = (size_t)(n0 + tn * 4 + i);
#pragma unroll
        for (int j = 0; j < 4; ++j) {
            C[row * O_ + (o0 + to * 4 + j)] = bfr(acc[i][j]);
        }
    }
}

__global__ __launch_bounds__(256) void sentinel_fill(float* __restrict__ C, size_t n, float v) {
    size_t i = (size_t)blockIdx.x * 256u + threadIdx.x;
    size_t stride = (size_t)gridDim.x * 256u;
    for (; i < n; i += stride) C[i] = v;
}

extern "C" void kernel_launch(void* const* d_in, const int* in_sizes, int n_in,
                              void* d_out, int out_size, void* d_ws, size_t ws_size,
                              hipStream_t stream) {
    const float* x = (const float*)d_in[0];
    const int* q = (const int*)d_in[1];
    const float* szf = (const float*)d_in[2];
    float* out = (float*)d_out;

    float sentinel = 0.0f;
    if (n_in < 3)                         sentinel = 1000.0f;
    else if (in_sizes[0] != 33554432)     sentinel = 2000.0f;  // x: 8192*4096
    else if (in_sizes[1] != 45088768)     sentinel = 3000.0f;  // weight_q: 11008*4096
    else if (in_sizes[2] != 704512)       sentinel = 4000.0f;  // s&z: 32*11008*2
    else if (out_size   != 90177536)      sentinel = 5000.0f;  // 8192*11008

    if (sentinel != 0.0f) {
        sentinel_fill<<<8192, 256, 0, stream>>>(out, (size_t)out_size, sentinel);
        return;
    }

    const size_t xb_bytes = (size_t)N_ * K_ * 2;   // 67,108,864
    const size_t wb_bytes = (size_t)O_ * K_ * 2;   // 90,177,536

    if (ws_size >= xb_bytes + wb_bytes) {
        uint16_t* Xb = (uint16_t*)d_ws;
        uint16_t* Wb = (uint16_t*)((char*)d_ws + xb_bytes);
        xcast<<<4096, 256, 0, stream>>>(x, Xb);
        wdeq<<<4096, 256, 0, stream>>>(q, szf, Wb);
        dim3 grid(N_ / 256, O_ / 256);   // 32 x 43
        gemm_pipe<<<grid, 512, 0, stream>>>(Xb, Wb, out);
    } else {
        dim3 grid(N_ / 64, O_ / 64);
        gemm_probe_f32sz<<<grid, 256, 0, stream>>>(x, q, szf, out);
    }
}